// Round 1
// baseline (299.533 us; speedup 1.0000x reference)
//
#include <hip/hip_runtime.h>
#include <hip/hip_bf16.h>

// Pipeline: roi_align -> conv3x3(C=256->E=256, 3x3 spatial, pad 1) -> GroupNorm(8)
//           -> ReLU -> spatial mean -> head GEMM -> +spat +sym_emb -> per-sid fuse matvec.
// Sizes: B=2, C=E=256, S=3, L=5, N=128, HMAX=128.

// ---------------- batched tiled transpose (f32 -> f32) ----------------
__global__ void t_f32(const float* __restrict__ in, float* __restrict__ out,
                      int rows, int cols) {
    __shared__ float tile[32][33];
    size_t mat = (size_t)blockIdx.z * rows * cols;
    int bx = blockIdx.x * 32, by = blockIdx.y * 32;
    int tx = threadIdx.x, ty = threadIdx.y;
#pragma unroll
    for (int i = 0; i < 32; i += 8) {
        int r = by + ty + i, c = bx + tx;
        if (r < rows && c < cols) tile[ty + i][tx] = in[mat + (size_t)r * cols + c];
    }
    __syncthreads();
#pragma unroll
    for (int i = 0; i < 32; i += 8) {
        int r = bx + ty + i, c = by + tx;
        if (r < cols && c < rows) out[mat + (size_t)r * rows + c] = tile[tx][ty + i];
    }
}

// ---------------- tiled transpose f32 -> bf16 (conv weights) ----------------
__global__ void t_bf16(const float* __restrict__ in, __hip_bfloat16* __restrict__ out,
                       int rows, int cols) {
    __shared__ float tile[32][33];
    int bx = blockIdx.x * 32, by = blockIdx.y * 32;
    int tx = threadIdx.x, ty = threadIdx.y;
#pragma unroll
    for (int i = 0; i < 32; i += 8) {
        int r = by + ty + i, c = bx + tx;
        if (r < rows && c < cols) tile[ty + i][tx] = in[(size_t)r * cols + c];
    }
    __syncthreads();
#pragma unroll
    for (int i = 0; i < 32; i += 8) {
        int r = bx + ty + i, c = by + tx;
        if (r < cols && c < rows) out[(size_t)r * rows + c] = __float2bfloat16(tile[tx][ty + i]);
    }
}

// ---------------- ROI align: one block per (n, grid point p) ----------------
// roiT layout: [n][p][c], p = i*3 + j (i = y index, j = x index)
__global__ __launch_bounds__(256) void roi_align_k(
    const float* __restrict__ fm, const float* __restrict__ boxes,
    const int* __restrict__ batch_idx, const int* __restrict__ level_idx,
    float* __restrict__ roiT) {
    int blk = blockIdx.x;
    int n = blk / 9, p = blk % 9;
    int i = p / 3, j = p % 3;
    int c = threadIdx.x;

    int lvl = level_idx[n];
    int b = batch_idx[n];
    const float sizes[5]  = {128.f, 64.f, 32.f, 16.f, 8.f};
    const float invstr[5] = {1.f/8.f, 1.f/16.f, 1.f/32.f, 1.f/64.f, 1.f/128.f};
    float scale = invstr[lvl];
    float hv = sizes[lvl];

    float x1 = boxes[n*4+0] * scale, y1 = boxes[n*4+1] * scale;
    float x2 = boxes[n*4+2] * scale, y2 = boxes[n*4+3] * scale;
    float rw = fmaxf(x2 - x1, 1.f), rh = fmaxf(y2 - y1, 1.f);
    float x = x1 + (((float)j + 0.5f) / 3.f) * rw;
    float y = y1 + (((float)i + 0.5f) / 3.f) * rh;

    bool valid = (y > -1.f) && (y < hv) && (x > -1.f) && (x < hv);
    float yc = fminf(fmaxf(y, 0.f), hv - 1.f);
    float xc = fminf(fmaxf(x, 0.f), hv - 1.f);
    int y0 = (int)floorf(yc), x0 = (int)floorf(xc);
    int hi = (int)(hv - 1.f);
    int y1i = min(y0 + 1, hi), x1i = min(x0 + 1, hi);
    float ly = yc - (float)y0, lx = xc - (float)x0;

    const float* base = fm + (((size_t)lvl * 2 + b) * 256 + c) * (128 * 128);
    float v00 = base[y0 * 128 + x0];
    float v01 = base[y0 * 128 + x1i];
    float v10 = base[y1i * 128 + x0];
    float v11 = base[y1i * 128 + x1i];
    float v = (1.f - ly) * (1.f - lx) * v00 + (1.f - ly) * lx * v01 +
              ly * (1.f - lx) * v10 + ly * lx * v11;
    roiT[((size_t)n * 9 + p) * 256 + c] = valid ? v : 0.f;
}

// ---------------- conv3x3 + GroupNorm + ReLU + spatial-mean ----------------
// Block = (n, e-half): 256 blocks x 512 threads. thread: e_loc = t&127, ch = t>>7
// (c-quarter). GN group = e/32: each e-half block holds 4 complete groups.
__global__ __launch_bounds__(512) void conv_gn_pool(
    const float* __restrict__ roiT, const __hip_bfloat16* __restrict__ w_t,
    const float* __restrict__ gn_scale, const float* __restrict__ gn_bias,
    float* __restrict__ pooled) {
    __shared__ float lds_roi[256 * 12];   // [c][p], padded to 12 for 16B rows
    __shared__ float red[2 * 128 * 9];

    int n  = blockIdx.x >> 1;
    int eh = blockIdx.x & 1;
    int t = threadIdx.x;
    int e_loc = t & 127;
    int ch = t >> 7;                      // 0..3, c-range [ch*64, ch*64+64)
    int e = eh * 128 + e_loc;

    const float* rsrc = roiT + (size_t)n * 2304;
    for (int v = t; v < 2304; v += 512) { // v = p*256 + c
        int p = v >> 8, c = v & 255;
        lds_roi[c * 12 + p] = rsrc[v];
    }
    __syncthreads();

    float acc[9];
#pragma unroll
    for (int p = 0; p < 9; ++p) acc[p] = 0.f;

    int c0 = ch * 64;
    for (int c = c0; c < c0 + 64; ++c) {
        float r[9];
#pragma unroll
        for (int jj = 0; jj < 9; ++jj) r[jj] = lds_roi[c * 12 + jj];
        const __hip_bfloat16* wr = w_t + (size_t)c * 9 * 256 + e;
#pragma unroll
        for (int ky = 0; ky < 3; ++ky) {
#pragma unroll
            for (int kx = 0; kx < 3; ++kx) {
                float wv = __bfloat162float(wr[(ky * 3 + kx) * 256]);
#pragma unroll
                for (int oy = 0; oy < 3; ++oy) {
                    int iy = oy + ky - 1;
                    if (iy < 0 || iy > 2) continue;
#pragma unroll
                    for (int ox = 0; ox < 3; ++ox) {
                        int ix = ox + kx - 1;
                        if (ix < 0 || ix > 2) continue;
                        acc[oy * 3 + ox] = fmaf(wv, r[iy * 3 + ix], acc[oy * 3 + ox]);
                    }
                }
            }
        }
    }

    // tree-reduce the 4 c-quarters into ch==0
    if (ch >= 2) {
#pragma unroll
        for (int p = 0; p < 9; ++p) red[((ch - 2) * 128 + e_loc) * 9 + p] = acc[p];
    }
    __syncthreads();
    if (ch < 2) {
#pragma unroll
        for (int p = 0; p < 9; ++p) acc[p] += red[(ch * 128 + e_loc) * 9 + p];
    }
    __syncthreads();
    if (ch == 1) {
#pragma unroll
        for (int p = 0; p < 9; ++p) red[e_loc * 9 + p] = acc[p];
    }
    __syncthreads();
    if (ch == 0) {
#pragma unroll
        for (int p = 0; p < 9; ++p) acc[p] += red[e_loc * 9 + p];

        // GroupNorm: group = e/32 -> 32 consecutive lanes (32-lane half of a wave)
        float s = 0.f, sq = 0.f;
#pragma unroll
        for (int p = 0; p < 9; ++p) { s += acc[p]; sq += acc[p] * acc[p]; }
#pragma unroll
        for (int m = 16; m >= 1; m >>= 1) {
            s  += __shfl_xor(s, m, 64);
            sq += __shfl_xor(sq, m, 64);
        }
        float mean = s * (1.f / 288.f);
        float var = sq * (1.f / 288.f) - mean * mean;
        float rinv = rsqrtf(var + 1e-5f);
        float gs = gn_scale[e], gb = gn_bias[e];
        float ps = 0.f;
#pragma unroll
        for (int p = 0; p < 9; ++p) {
            float v = (acc[p] - mean) * rinv * gs + gb;
            ps += fmaxf(v, 0.f);
        }
        pooled[(size_t)n * 256 + e] = ps * (1.f / 9.f);
    }
}

// ---------------- head GEMM + spat + sym_emb + fuse matvec ----------------
__global__ __launch_bounds__(256) void head_fuse(
    const float* __restrict__ pooled, const float* __restrict__ boxes,
    const float* __restrict__ head_wT, const float* __restrict__ head_b,
    const float* __restrict__ spat_w, const float* __restrict__ spat_b,
    const float* __restrict__ sym_emb,
    const float* __restrict__ fuse_wT, const float* __restrict__ fuse_b,
    const int* __restrict__ sym_ids, float* __restrict__ out) {
    __shared__ float pl[256];
    __shared__ float fin[256];
    int n = blockIdx.x;
    int t = threadIdx.x;
    int sid = sym_ids[n];

    pl[t] = pooled[(size_t)n * 256 + t];
    __syncthreads();

    float acc = head_b[t];
#pragma unroll 4
    for (int k = 0; k < 256; ++k) acc = fmaf(pl[k], head_wT[k * 256 + t], acc);
    float ho = fmaxf(acc, 0.f);

    float4 sw = ((const float4*)spat_w)[t];
    float b0 = boxes[n*4+0], b1 = boxes[n*4+1], b2 = boxes[n*4+2], b3 = boxes[n*4+3];
    float sp = fmaxf(spat_b[t] + b0*sw.x + b1*sw.y + b2*sw.z + b3*sw.w, 0.f);

    fin[t] = ho + sp + sym_emb[sid * 256 + t];
    __syncthreads();

    float o = fuse_b[sid * 256 + t];
    const float* fw = fuse_wT + (size_t)sid * 65536;
#pragma unroll 4
    for (int k = 0; k < 256; ++k) o = fmaf(fin[k], fw[k * 256 + t], o);
    out[(size_t)n * 256 + t] = fmaxf(o, 0.f);
}

extern "C" void kernel_launch(void* const* d_in, const int* in_sizes, int n_in,
                              void* d_out, int out_size, void* d_ws, size_t ws_size,
                              hipStream_t stream) {
    const float* fm      = (const float*)d_in[0];
    const float* boxes   = (const float*)d_in[1];
    const float* conv_w  = (const float*)d_in[2];
    const float* gn_s    = (const float*)d_in[3];
    const float* gn_b    = (const float*)d_in[4];
    const float* head_w  = (const float*)d_in[5];
    const float* head_b  = (const float*)d_in[6];
    const float* spat_w  = (const float*)d_in[7];
    const float* spat_b  = (const float*)d_in[8];
    const float* sym_emb = (const float*)d_in[9];
    const float* fuse_w  = (const float*)d_in[10];
    const float* fuse_b  = (const float*)d_in[11];
    const int* batch_idx = (const int*)d_in[12];
    const int* level_idx = (const int*)d_in[13];
    const int* sym_ids   = (const int*)d_in[14];
    float* outp = (float*)d_out;

    char* ws = (char*)d_ws;
    __hip_bfloat16* w_t = (__hip_bfloat16*)ws;        // [2304][256] bf16: 1,179,648 B
    float* head_wT = (float*)(ws + 1179648);          // [256][256]      :   262,144 B
    float* fuse_wT = (float*)(ws + 1441792);          // [6][256][256]   : 1,572,864 B
    float* roiT    = (float*)(ws + 3014656);          // [128][9][256]   : 1,179,648 B
    float* pooled  = (float*)(ws + 4194304);          // [128][256]      :   131,072 B

    t_bf16<<<dim3(72, 8, 1), dim3(32, 8), 0, stream>>>(conv_w, w_t, 256, 2304);
    t_f32 <<<dim3(8, 8, 1),  dim3(32, 8), 0, stream>>>(head_w, head_wT, 256, 256);
    t_f32 <<<dim3(8, 8, 6),  dim3(32, 8), 0, stream>>>(fuse_w, fuse_wT, 256, 256);
    roi_align_k<<<1152, 256, 0, stream>>>(fm, boxes, batch_idx, level_idx, roiT);
    conv_gn_pool<<<256, 512, 0, stream>>>(roiT, w_t, gn_s, gn_b, pooled);
    head_fuse<<<128, 256, 0, stream>>>(pooled, boxes, head_wT, head_b, spat_w, spat_b,
                                       sym_emb, fuse_wT, fuse_b, sym_ids, outp);
}

// Round 2
// 273.565 us; speedup vs baseline: 1.0949x; 1.0949x over previous
//
#include <hip/hip_runtime.h>
#include <hip/hip_bf16.h>

// Pipeline: roi_align -> conv3x3(C=256->E=256 on 3x3 spatial, pad 1) -> GroupNorm(8)
//           -> ReLU -> spatial mean -> head GEMM -> +spat +sym_emb -> per-sid fuse matvec.
// Sizes: B=2, C=E=256, S=3, L=5, N=128, HMAX=128.

__device__ __forceinline__ float bf_lo(unsigned u) { return __uint_as_float(u << 16); }
__device__ __forceinline__ float bf_hi(unsigned u) { return __uint_as_float(u & 0xffff0000u); }
__device__ __forceinline__ unsigned short f2bf(float f) {
    __hip_bfloat16 h = __float2bfloat16(f);
    return *(unsigned short*)&h;
}

// ---------------- weight repack: conv_w [e][c][9] f32 -> w8 [c][e][8] + w9 [c][e] bf16 ----
// block = c (256), thread = e (256). Writes coalesced (16B/lane dense).
__global__ __launch_bounds__(256) void w_prep(const float* __restrict__ conv_w,
                                              unsigned short* __restrict__ w8,
                                              unsigned short* __restrict__ w9) {
    int c = blockIdx.x, e = threadIdx.x;
    const float* src = conv_w + ((size_t)e * 256 + c) * 9;
    unsigned short tmp[8];
#pragma unroll
    for (int k = 0; k < 8; ++k) tmp[k] = f2bf(src[k]);
    ((uint4*)w8)[(size_t)c * 256 + e] = *(const uint4*)tmp;
    w9[(size_t)c * 256 + e] = f2bf(src[8]);
}

// ---------------- batched tiled transpose f32 (head_w z=0, fuse_w z=1..6) ----------------
__global__ void t7(const float* __restrict__ head_w, const float* __restrict__ fuse_w,
                   float* __restrict__ head_wT, float* __restrict__ fuse_wT) {
    __shared__ float tile[32][33];
    int z = blockIdx.z;
    const float* in = (z == 0) ? head_w : fuse_w + (size_t)(z - 1) * 65536;
    float* out = (z == 0) ? head_wT : fuse_wT + (size_t)(z - 1) * 65536;
    int bx = blockIdx.x * 32, by = blockIdx.y * 32;
    int tx = threadIdx.x, ty = threadIdx.y;
#pragma unroll
    for (int i = 0; i < 32; i += 8)
        tile[ty + i][tx] = in[(size_t)(by + ty + i) * 256 + bx + tx];
    __syncthreads();
#pragma unroll
    for (int i = 0; i < 32; i += 8)
        out[(size_t)(bx + ty + i) * 256 + by + tx] = tile[tx][ty + i];
}

// ---------------- ROI align: one block per (n, grid point p) ----------------
// roiT layout: [n][p][c], p = i*3 + j
__global__ __launch_bounds__(256) void roi_align_k(
    const float* __restrict__ fm, const float* __restrict__ boxes,
    const int* __restrict__ batch_idx, const int* __restrict__ level_idx,
    float* __restrict__ roiT) {
    int blk = blockIdx.x;
    int n = blk / 9, p = blk % 9;
    int i = p / 3, j = p % 3;
    int c = threadIdx.x;

    int lvl = level_idx[n];
    int b = batch_idx[n];
    const float sizes[5]  = {128.f, 64.f, 32.f, 16.f, 8.f};
    const float invstr[5] = {1.f/8.f, 1.f/16.f, 1.f/32.f, 1.f/64.f, 1.f/128.f};
    float scale = invstr[lvl];
    float hv = sizes[lvl];

    float x1 = boxes[n*4+0] * scale, y1 = boxes[n*4+1] * scale;
    float x2 = boxes[n*4+2] * scale, y2 = boxes[n*4+3] * scale;
    float rw = fmaxf(x2 - x1, 1.f), rh = fmaxf(y2 - y1, 1.f);
    float x = x1 + (((float)j + 0.5f) / 3.f) * rw;
    float y = y1 + (((float)i + 0.5f) / 3.f) * rh;

    bool valid = (y > -1.f) && (y < hv) && (x > -1.f) && (x < hv);
    float yc = fminf(fmaxf(y, 0.f), hv - 1.f);
    float xc = fminf(fmaxf(x, 0.f), hv - 1.f);
    int y0 = (int)floorf(yc), x0 = (int)floorf(xc);
    int hi = (int)(hv - 1.f);
    int y1i = min(y0 + 1, hi), x1i = min(x0 + 1, hi);
    float ly = yc - (float)y0, lx = xc - (float)x0;

    const float* base = fm + (((size_t)lvl * 2 + b) * 256 + c) * (128 * 128);
    float v00 = base[y0 * 128 + x0];
    float v01 = base[y0 * 128 + x1i];
    float v10 = base[y1i * 128 + x0];
    float v11 = base[y1i * 128 + x1i];
    float v = (1.f - ly) * (1.f - lx) * v00 + (1.f - ly) * lx * v01 +
              ly * (1.f - lx) * v10 + ly * lx * v11;
    roiT[((size_t)n * 9 + p) * 256 + c] = valid ? v : 0.f;
}

// ---------------- conv3x3 + GroupNorm + ReLU + spatial-mean ----------------
// Block = (n, e-quarter): 512 blocks x 512 threads (2 blocks/CU, 4 waves/SIMD).
// thread: e_loc = t&63, ch = t>>6 (one of 8 c-slices of 32 channels each).
// GN group = e/32: e-quarter = 64 e's = 2 complete groups; ch==0 wave has lane==e_loc,
// groups live in 32-lane halves so shfl_xor masks <=16 stay in-group.
__global__ __launch_bounds__(512, 2) void conv_gn_pool(
    const float* __restrict__ roiT,
    const unsigned short* __restrict__ w8, const unsigned short* __restrict__ w9,
    const float* __restrict__ gn_scale, const float* __restrict__ gn_bias,
    float* __restrict__ pooled) {
    __shared__ float lds_roi[256 * 12];   // [c][p], stride 12
    __shared__ float red[4 * 64 * 9];

    int n  = blockIdx.x >> 2;
    int eq = blockIdx.x & 3;
    int t = threadIdx.x;
    int e_loc = t & 63;
    int ch = t >> 6;                      // 0..7, c-range [ch*32, ch*32+32)
    int e = eq * 64 + e_loc;

    const float* rsrc = roiT + (size_t)n * 2304;
    for (int v = t; v < 2304; v += 512) { // v = p*256 + c
        int p = v >> 8, c = v & 255;
        lds_roi[c * 12 + p] = rsrc[v];
    }
    __syncthreads();

    float acc[9];
#pragma unroll
    for (int p = 0; p < 9; ++p) acc[p] = 0.f;

    int c0 = ch * 32;
    for (int c = c0; c < c0 + 32; ++c) {
        float r[9];
#pragma unroll
        for (int jj = 0; jj < 9; ++jj) r[jj] = lds_roi[c * 12 + jj];
        uint4 wa = ((const uint4*)w8)[(size_t)c * 256 + e];
        unsigned short w9v = w9[(size_t)c * 256 + e];
        float wv[9];
        wv[0] = bf_lo(wa.x); wv[1] = bf_hi(wa.x);
        wv[2] = bf_lo(wa.y); wv[3] = bf_hi(wa.y);
        wv[4] = bf_lo(wa.z); wv[5] = bf_hi(wa.z);
        wv[6] = bf_lo(wa.w); wv[7] = bf_hi(wa.w);
        wv[8] = bf_lo((unsigned)w9v);
#pragma unroll
        for (int ky = 0; ky < 3; ++ky) {
#pragma unroll
            for (int kx = 0; kx < 3; ++kx) {
                float w = wv[ky * 3 + kx];
#pragma unroll
                for (int oy = 0; oy < 3; ++oy) {
                    int iy = oy + ky - 1;
                    if (iy < 0 || iy > 2) continue;
#pragma unroll
                    for (int ox = 0; ox < 3; ++ox) {
                        int ix = ox + kx - 1;
                        if (ix < 0 || ix > 2) continue;
                        acc[oy * 3 + ox] = fmaf(w, r[iy * 3 + ix], acc[oy * 3 + ox]);
                    }
                }
            }
        }
    }

    // tree-reduce 8 c-slices into ch==0
    if (ch >= 4) {
#pragma unroll
        for (int p = 0; p < 9; ++p) red[((ch - 4) * 64 + e_loc) * 9 + p] = acc[p];
    }
    __syncthreads();
    if (ch < 4) {
#pragma unroll
        for (int p = 0; p < 9; ++p) acc[p] += red[(ch * 64 + e_loc) * 9 + p];
    }
    __syncthreads();
    if (ch >= 2 && ch < 4) {
#pragma unroll
        for (int p = 0; p < 9; ++p) red[((ch - 2) * 64 + e_loc) * 9 + p] = acc[p];
    }
    __syncthreads();
    if (ch < 2) {
#pragma unroll
        for (int p = 0; p < 9; ++p) acc[p] += red[(ch * 64 + e_loc) * 9 + p];
    }
    __syncthreads();
    if (ch == 1) {
#pragma unroll
        for (int p = 0; p < 9; ++p) red[e_loc * 9 + p] = acc[p];
    }
    __syncthreads();
    if (ch == 0) {
#pragma unroll
        for (int p = 0; p < 9; ++p) acc[p] += red[e_loc * 9 + p];

        float s = 0.f, sq = 0.f;
#pragma unroll
        for (int p = 0; p < 9; ++p) { s += acc[p]; sq += acc[p] * acc[p]; }
#pragma unroll
        for (int m = 16; m >= 1; m >>= 1) {
            s  += __shfl_xor(s, m, 64);
            sq += __shfl_xor(sq, m, 64);
        }
        float mean = s * (1.f / 288.f);
        float var = sq * (1.f / 288.f) - mean * mean;
        float rinv = rsqrtf(var + 1e-5f);
        float gs = gn_scale[e], gb = gn_bias[e];
        float ps = 0.f;
#pragma unroll
        for (int p = 0; p < 9; ++p) {
            float v = (acc[p] - mean) * rinv * gs + gb;
            ps += fmaxf(v, 0.f);
        }
        pooled[(size_t)n * 256 + e] = ps * (1.f / 9.f);
    }
}

// ---------------- head GEMM + spat + sym_emb + fuse matvec ----------------
__global__ __launch_bounds__(256) void head_fuse(
    const float* __restrict__ pooled, const float* __restrict__ boxes,
    const float* __restrict__ head_wT, const float* __restrict__ head_b,
    const float* __restrict__ spat_w, const float* __restrict__ spat_b,
    const float* __restrict__ sym_emb,
    const float* __restrict__ fuse_wT, const float* __restrict__ fuse_b,
    const int* __restrict__ sym_ids, float* __restrict__ out) {
    __shared__ float pl[256];
    __shared__ float fin[256];
    int n = blockIdx.x;
    int t = threadIdx.x;
    int sid = sym_ids[n];

    pl[t] = pooled[(size_t)n * 256 + t];
    __syncthreads();

    float acc = head_b[t];
#pragma unroll 8
    for (int k = 0; k < 256; ++k) acc = fmaf(pl[k], head_wT[k * 256 + t], acc);
    float ho = fmaxf(acc, 0.f);

    float4 sw = ((const float4*)spat_w)[t];
    float b0 = boxes[n*4+0], b1 = boxes[n*4+1], b2 = boxes[n*4+2], b3 = boxes[n*4+3];
    float sp = fmaxf(spat_b[t] + b0*sw.x + b1*sw.y + b2*sw.z + b3*sw.w, 0.f);

    fin[t] = ho + sp + sym_emb[sid * 256 + t];
    __syncthreads();

    float o = fuse_b[sid * 256 + t];
    const float* fw = fuse_wT + (size_t)sid * 65536;
#pragma unroll 8
    for (int k = 0; k < 256; ++k) o = fmaf(fin[k], fw[k * 256 + t], o);
    out[(size_t)n * 256 + t] = fmaxf(o, 0.f);
}

extern "C" void kernel_launch(void* const* d_in, const int* in_sizes, int n_in,
                              void* d_out, int out_size, void* d_ws, size_t ws_size,
                              hipStream_t stream) {
    const float* fm      = (const float*)d_in[0];
    const float* boxes   = (const float*)d_in[1];
    const float* conv_w  = (const float*)d_in[2];
    const float* gn_s    = (const float*)d_in[3];
    const float* gn_b    = (const float*)d_in[4];
    const float* head_w  = (const float*)d_in[5];
    const float* head_b  = (const float*)d_in[6];
    const float* spat_w  = (const float*)d_in[7];
    const float* spat_b  = (const float*)d_in[8];
    const float* sym_emb = (const float*)d_in[9];
    const float* fuse_w  = (const float*)d_in[10];
    const float* fuse_b  = (const float*)d_in[11];
    const int* batch_idx = (const int*)d_in[12];
    const int* level_idx = (const int*)d_in[13];
    const int* sym_ids   = (const int*)d_in[14];
    float* outp = (float*)d_out;

    char* ws = (char*)d_ws;
    unsigned short* w8 = (unsigned short*)ws;        // [256c][256e][8] bf16: 1,048,576 B
    unsigned short* w9 = (unsigned short*)(ws + 1048576); // [256c][256e] bf16:  131,072 B
    float* head_wT = (float*)(ws + 1179648);         // [256][256]          :  262,144 B
    float* fuse_wT = (float*)(ws + 1441792);         // [6][256][256]       :1,572,864 B
    float* roiT    = (float*)(ws + 3014656);         // [128][9][256]       :1,179,648 B
    float* pooled  = (float*)(ws + 4194304);         // [128][256]          :  131,072 B

    w_prep<<<256, 256, 0, stream>>>(conv_w, w8, w9);
    t7<<<dim3(8, 8, 7), dim3(32, 8), 0, stream>>>(head_w, fuse_w, head_wT, fuse_wT);
    roi_align_k<<<1152, 256, 0, stream>>>(fm, boxes, batch_idx, level_idx, roiT);
    conv_gn_pool<<<512, 512, 0, stream>>>(roiT, w8, w9, gn_s, gn_b, pooled);
    head_fuse<<<128, 256, 0, stream>>>(pooled, boxes, head_wT, head_b, spat_w, spat_b,
                                       sym_emb, fuse_wT, fuse_b, sym_ids, outp);
}

// Round 3
// 261.857 us; speedup vs baseline: 1.1439x; 1.0447x over previous
//
#include <hip/hip_runtime.h>
#include <hip/hip_bf16.h>

// Pipeline: roi_align -> conv3x3(C=256->E=256 on 3x3 spatial, pad 1) -> GroupNorm(8)
//           -> ReLU -> spatial mean -> head GEMM -> +spat +sym_emb -> per-sid fuse matvec.
// Sizes: B=2, C=E=256, S=3, L=5, N=128, HMAX=128.
// 3 launches: prep(w_prep+t7+roi fused) -> conv_gn_pool -> head_fuse.

__device__ __forceinline__ float bf_lo(unsigned u) { return __uint_as_float(u << 16); }
__device__ __forceinline__ float bf_hi(unsigned u) { return __uint_as_float(u & 0xffff0000u); }
__device__ __forceinline__ unsigned short f2bf(float f) {
    __hip_bfloat16 h = __float2bfloat16(f);
    return *(unsigned short*)&h;
}

// ---------------- fused prep kernel ----------------
// grid.x partition: [0,256)   w_prep  (block=c, thread=e)
//                   [256,704) t7      (448 transpose tiles: head_w + 6x fuse_w)
//                   [704,1856) roi    (block=(n,p), thread=c)
__global__ __launch_bounds__(256) void prep_k(
    const float* __restrict__ conv_w,
    const float* __restrict__ head_w, const float* __restrict__ fuse_w,
    const float* __restrict__ fm, const float* __restrict__ boxes,
    const int* __restrict__ batch_idx, const int* __restrict__ level_idx,
    unsigned short* __restrict__ w8, unsigned short* __restrict__ w9,
    float* __restrict__ head_wT, float* __restrict__ fuse_wT,
    float* __restrict__ roiT) {
    int blk = blockIdx.x;
    int t = threadIdx.x;

    if (blk < 256) {
        // ---- conv weight repack: [e][c][9] f32 -> w8[c][e][8] + w9[c][e] bf16 ----
        int c = blk, e = t;
        const float* src = conv_w + ((size_t)e * 256 + c) * 9;
        unsigned short tmp[8];
#pragma unroll
        for (int k = 0; k < 8; ++k) tmp[k] = f2bf(src[k]);
        ((uint4*)w8)[(size_t)c * 256 + e] = *(const uint4*)tmp;
        w9[(size_t)c * 256 + e] = f2bf(src[8]);
        return;
    }

    if (blk < 704) {
        // ---- 32x32 tiled transpose of head_w (z=0) / fuse_w (z=1..6) ----
        __shared__ float tile[32][33];
        int q = blk - 256;
        int z = q >> 6;               // 0..6
        int rem = q & 63;
        int bx = (rem & 7) * 32, by = (rem >> 3) * 32;
        const float* in = (z == 0) ? head_w : fuse_w + (size_t)(z - 1) * 65536;
        float* out = (z == 0) ? head_wT : fuse_wT + (size_t)(z - 1) * 65536;
        int tx = t & 31, ty = t >> 5;
#pragma unroll
        for (int i = 0; i < 32; i += 8)
            tile[ty + i][tx] = in[(size_t)(by + ty + i) * 256 + bx + tx];
        __syncthreads();
#pragma unroll
        for (int i = 0; i < 32; i += 8)
            out[(size_t)(bx + ty + i) * 256 + by + tx] = tile[tx][ty + i];
        return;
    }

    // ---- ROI align: roiT[n][p][c], p = i*3 + j ----
    {
        int q = blk - 704;
        int n = q / 9, p = q % 9;
        int i = p / 3, j = p % 3;
        int c = t;

        int lvl = level_idx[n];
        int b = batch_idx[n];
        const float sizes[5]  = {128.f, 64.f, 32.f, 16.f, 8.f};
        const float invstr[5] = {1.f/8.f, 1.f/16.f, 1.f/32.f, 1.f/64.f, 1.f/128.f};
        float scale = invstr[lvl];
        float hv = sizes[lvl];

        float x1 = boxes[n*4+0] * scale, y1 = boxes[n*4+1] * scale;
        float x2 = boxes[n*4+2] * scale, y2 = boxes[n*4+3] * scale;
        float rw = fmaxf(x2 - x1, 1.f), rh = fmaxf(y2 - y1, 1.f);
        float x = x1 + (((float)j + 0.5f) / 3.f) * rw;
        float y = y1 + (((float)i + 0.5f) / 3.f) * rh;

        bool valid = (y > -1.f) && (y < hv) && (x > -1.f) && (x < hv);
        float yc = fminf(fmaxf(y, 0.f), hv - 1.f);
        float xc = fminf(fmaxf(x, 0.f), hv - 1.f);
        int y0 = (int)floorf(yc), x0 = (int)floorf(xc);
        int hi = (int)(hv - 1.f);
        int y1i = min(y0 + 1, hi), x1i = min(x0 + 1, hi);
        float ly = yc - (float)y0, lx = xc - (float)x0;

        const float* base = fm + (((size_t)lvl * 2 + b) * 256 + c) * (128 * 128);
        float v00 = base[y0 * 128 + x0];
        float v01 = base[y0 * 128 + x1i];
        float v10 = base[y1i * 128 + x0];
        float v11 = base[y1i * 128 + x1i];
        float v = (1.f - ly) * (1.f - lx) * v00 + (1.f - ly) * lx * v01 +
                  ly * (1.f - lx) * v10 + ly * lx * v11;
        roiT[((size_t)n * 9 + p) * 256 + c] = valid ? v : 0.f;
    }
}

// ---------------- conv3x3 + GroupNorm + ReLU + spatial-mean ----------------
// Block = (n, e-quarter): 512 blocks x 512 threads (2 blocks/CU, 4 waves/SIMD).
// thread: e_loc = t&63, ch = t>>6 (one of 8 c-slices of 32 channels each).
// GN group = e/32: ch==0 wave has lane==e_loc, groups in 32-lane halves so
// shfl_xor masks <=16 stay in-group.
__global__ __launch_bounds__(512, 2) void conv_gn_pool(
    const float* __restrict__ roiT,
    const unsigned short* __restrict__ w8, const unsigned short* __restrict__ w9,
    const float* __restrict__ gn_scale, const float* __restrict__ gn_bias,
    float* __restrict__ pooled) {
    __shared__ float lds_roi[256 * 12];   // [c][p], stride 12
    __shared__ float red[4 * 64 * 9];

    int n  = blockIdx.x >> 2;
    int eq = blockIdx.x & 3;
    int t = threadIdx.x;
    int e_loc = t & 63;
    int ch = t >> 6;                      // 0..7, c-range [ch*32, ch*32+32)
    int e = eq * 64 + e_loc;

    const float* rsrc = roiT + (size_t)n * 2304;
    for (int v = t; v < 2304; v += 512) { // v = p*256 + c
        int p = v >> 8, c = v & 255;
        lds_roi[c * 12 + p] = rsrc[v];
    }
    __syncthreads();

    float acc[9];
#pragma unroll
    for (int p = 0; p < 9; ++p) acc[p] = 0.f;

    int c0 = ch * 32;
    for (int c = c0; c < c0 + 32; ++c) {
        float r[9];
#pragma unroll
        for (int jj = 0; jj < 9; ++jj) r[jj] = lds_roi[c * 12 + jj];
        uint4 wa = ((const uint4*)w8)[(size_t)c * 256 + e];
        unsigned short w9v = w9[(size_t)c * 256 + e];
        float wv[9];
        wv[0] = bf_lo(wa.x); wv[1] = bf_hi(wa.x);
        wv[2] = bf_lo(wa.y); wv[3] = bf_hi(wa.y);
        wv[4] = bf_lo(wa.z); wv[5] = bf_hi(wa.z);
        wv[6] = bf_lo(wa.w); wv[7] = bf_hi(wa.w);
        wv[8] = bf_lo((unsigned)w9v);
#pragma unroll
        for (int ky = 0; ky < 3; ++ky) {
#pragma unroll
            for (int kx = 0; kx < 3; ++kx) {
                float w = wv[ky * 3 + kx];
#pragma unroll
                for (int oy = 0; oy < 3; ++oy) {
                    int iy = oy + ky - 1;
                    if (iy < 0 || iy > 2) continue;
#pragma unroll
                    for (int ox = 0; ox < 3; ++ox) {
                        int ix = ox + kx - 1;
                        if (ix < 0 || ix > 2) continue;
                        acc[oy * 3 + ox] = fmaf(w, r[iy * 3 + ix], acc[oy * 3 + ox]);
                    }
                }
            }
        }
    }

    // tree-reduce 8 c-slices into ch==0
    if (ch >= 4) {
#pragma unroll
        for (int p = 0; p < 9; ++p) red[((ch - 4) * 64 + e_loc) * 9 + p] = acc[p];
    }
    __syncthreads();
    if (ch < 4) {
#pragma unroll
        for (int p = 0; p < 9; ++p) acc[p] += red[(ch * 64 + e_loc) * 9 + p];
    }
    __syncthreads();
    if (ch >= 2 && ch < 4) {
#pragma unroll
        for (int p = 0; p < 9; ++p) red[((ch - 2) * 64 + e_loc) * 9 + p] = acc[p];
    }
    __syncthreads();
    if (ch < 2) {
#pragma unroll
        for (int p = 0; p < 9; ++p) acc[p] += red[(ch * 64 + e_loc) * 9 + p];
    }
    __syncthreads();
    if (ch == 1) {
#pragma unroll
        for (int p = 0; p < 9; ++p) red[e_loc * 9 + p] = acc[p];
    }
    __syncthreads();
    if (ch == 0) {
#pragma unroll
        for (int p = 0; p < 9; ++p) acc[p] += red[e_loc * 9 + p];

        float s = 0.f, sq = 0.f;
#pragma unroll
        for (int p = 0; p < 9; ++p) { s += acc[p]; sq += acc[p] * acc[p]; }
#pragma unroll
        for (int m = 16; m >= 1; m >>= 1) {
            s  += __shfl_xor(s, m, 64);
            sq += __shfl_xor(sq, m, 64);
        }
        float mean = s * (1.f / 288.f);
        float var = sq * (1.f / 288.f) - mean * mean;
        float rinv = rsqrtf(var + 1e-5f);
        float gs = gn_scale[e], gb = gn_bias[e];
        float ps = 0.f;
#pragma unroll
        for (int p = 0; p < 9; ++p) {
            float v = (acc[p] - mean) * rinv * gs + gb;
            ps += fmaxf(v, 0.f);
        }
        pooled[(size_t)n * 256 + e] = ps * (1.f / 9.f);
    }
}

// ---------------- head GEMM + spat + sym_emb + fuse matvec (k-split x2) ----------------
// block = n (128 blocks x 512 threads). t = kh*256 + e; each half-K matvec is 128 FMAs.
__global__ __launch_bounds__(512) void head_fuse(
    const float* __restrict__ pooled, const float* __restrict__ boxes,
    const float* __restrict__ head_wT, const float* __restrict__ head_b,
    const float* __restrict__ spat_w, const float* __restrict__ spat_b,
    const float* __restrict__ sym_emb,
    const float* __restrict__ fuse_wT, const float* __restrict__ fuse_b,
    const int* __restrict__ sym_ids, float* __restrict__ out) {
    __shared__ float pl[256];
    __shared__ float part[512];
    __shared__ float fin[256];
    int n = blockIdx.x;
    int t = threadIdx.x;
    int e = t & 255;
    int kh = t >> 8;                      // 0/1
    int sid = sym_ids[n];

    if (t < 256) pl[t] = pooled[(size_t)n * 256 + t];
    __syncthreads();

    {
        float acc = 0.f;
        const float* w = head_wT + (size_t)(kh * 128) * 256 + e;
        const float* p = pl + kh * 128;
#pragma unroll 8
        for (int k = 0; k < 128; ++k) acc = fmaf(p[k], w[k * 256], acc);
        part[t] = acc;
    }
    __syncthreads();
    if (t < 256) {
        float ho = fmaxf(part[t] + part[t + 256] + head_b[t], 0.f);
        float4 sw = ((const float4*)spat_w)[t];
        float b0 = boxes[n*4+0], b1 = boxes[n*4+1], b2 = boxes[n*4+2], b3 = boxes[n*4+3];
        float sp = fmaxf(spat_b[t] + b0*sw.x + b1*sw.y + b2*sw.z + b3*sw.w, 0.f);
        fin[t] = ho + sp + sym_emb[sid * 256 + t];
    }
    __syncthreads();
    {
        float o = 0.f;
        const float* w = fuse_wT + (size_t)sid * 65536 + (size_t)(kh * 128) * 256 + e;
        const float* p = fin + kh * 128;
#pragma unroll 8
        for (int k = 0; k < 128; ++k) o = fmaf(p[k], w[k * 256], o);
        part[t] = o;
    }
    __syncthreads();
    if (t < 256)
        out[(size_t)n * 256 + t] = fmaxf(part[t] + part[t + 256] + fuse_b[sid * 256 + t], 0.f);
}

extern "C" void kernel_launch(void* const* d_in, const int* in_sizes, int n_in,
                              void* d_out, int out_size, void* d_ws, size_t ws_size,
                              hipStream_t stream) {
    const float* fm      = (const float*)d_in[0];
    const float* boxes   = (const float*)d_in[1];
    const float* conv_w  = (const float*)d_in[2];
    const float* gn_s    = (const float*)d_in[3];
    const float* gn_b    = (const float*)d_in[4];
    const float* head_w  = (const float*)d_in[5];
    const float* head_b  = (const float*)d_in[6];
    const float* spat_w  = (const float*)d_in[7];
    const float* spat_b  = (const float*)d_in[8];
    const float* sym_emb = (const float*)d_in[9];
    const float* fuse_w  = (const float*)d_in[10];
    const float* fuse_b  = (const float*)d_in[11];
    const int* batch_idx = (const int*)d_in[12];
    const int* level_idx = (const int*)d_in[13];
    const int* sym_ids   = (const int*)d_in[14];
    float* outp = (float*)d_out;

    char* ws = (char*)d_ws;
    unsigned short* w8 = (unsigned short*)ws;             // [256c][256e][8] bf16: 1,048,576 B
    unsigned short* w9 = (unsigned short*)(ws + 1048576); // [256c][256e] bf16  :   131,072 B
    float* head_wT = (float*)(ws + 1179648);              // [256][256]         :   262,144 B
    float* fuse_wT = (float*)(ws + 1441792);              // [6][256][256]      : 1,572,864 B
    float* roiT    = (float*)(ws + 3014656);              // [128][9][256]      : 1,179,648 B
    float* pooled  = (float*)(ws + 4194304);              // [128][256]         :   131,072 B

    prep_k<<<1856, 256, 0, stream>>>(conv_w, head_w, fuse_w, fm, boxes,
                                     batch_idx, level_idx,
                                     w8, w9, head_wT, fuse_wT, roiT);
    conv_gn_pool<<<512, 512, 0, stream>>>(roiT, w8, w9, gn_s, gn_b, pooled);
    head_fuse<<<128, 512, 0, stream>>>(pooled, boxes, head_wT, head_b, spat_w, spat_b,
                                       sym_emb, fuse_wT, fuse_b, sym_ids, outp);
}